// Round 1
// 202.557 us; speedup vs baseline: 1.0054x; 1.0054x over previous
//
#include <hip/hip_runtime.h>
#include <stdint.h>
#include <stddef.h>

// DynamicRouter: logits = x @ W^T / T; top-2; softmax; scatter.
// B=8192, D=4096, E=64, K=2.
// R5: kRows 16->32 (grid 512->256 blocks) halves the per-block w-fragment
// L2 re-read (512 MiB -> 256 MiB) to get the per-CU TA/L1 vector path
// (~120 GB/s -> ~72 GB/s) off the critical path. LDS x rows are unpadded
// (2*32*256 fl = 64 KiB exactly, static limit) with both-sides XOR swizzle:
// glds16 keeps a linear LDS dest + pre-swizzled per-lane GLOBAL source
// ((lane*4)^((row&7)<<2) floats), ds_read applies the same XOR -> same
// 2-way bank profile as the old 260-stride pad. Per-row math is bitwise
// identical to R4 (same step<->wave map, same 4-term MFMA order, same
// ascending-wave partial sum), so absmax should be unchanged.

typedef __attribute__((ext_vector_type(8))) short short8;   // 8 bf16 (4 VGPRs)
typedef __attribute__((ext_vector_type(4))) float f32x4;    // MFMA accumulator

static constexpr int kB = 8192;
static constexpr int kD = 4096;
static constexpr int kE = 64;
static constexpr int kSteps = kD / 32;      // 128 K-steps of 32
static constexpr int kWv = 8;               // waves per block
static constexpr int kRows = 32;            // rows per block (R5: was 16)
static constexpr int kBK = 256;             // K per buffer (8 waves x 32)
static constexpr int kBufs = kD / kBK;      // 16 buffers
static constexpr int kRowF = 256;           // floats per LDS row, NO pad (XOR swizzle)

__device__ __forceinline__ uint32_t bf16_rne(float v) {
    uint32_t u = __builtin_bit_cast(uint32_t, v);
    return (u + 0x7FFFu + ((u >> 16) & 1u)) >> 16;
}

// fp32x8 -> bf16 hi/lo split (hi RNE; lo = RNE(exact residual))
__device__ __forceinline__ void cvt8(const f32x4& a0, const f32x4& a1,
                                     short8& ah, short8& al) {
#pragma unroll
    for (int j = 0; j < 4; ++j) {
        float xv = a0[j];
        uint32_t u  = __builtin_bit_cast(uint32_t, xv);
        uint32_t rh = (u + 0x7FFFu + ((u >> 16) & 1u)) & 0xFFFF0000u;
        ah[j] = (short)(rh >> 16);
        al[j] = (short)bf16_rne(xv - __builtin_bit_cast(float, rh));
        float yv = a1[j];
        uint32_t u2  = __builtin_bit_cast(uint32_t, yv);
        uint32_t rh2 = (u2 + 0x7FFFu + ((u2 >> 16) & 1u)) & 0xFFFF0000u;
        ah[j + 4] = (short)(rh2 >> 16);
        al[j + 4] = (short)bf16_rne(yv - __builtin_bit_cast(float, rh2));
    }
}

// async 16B global->LDS; LDS dest is wave-uniform base + lane*16 (HW rule).
__device__ __forceinline__ void glds16(const float* g, float* l) {
    __builtin_amdgcn_global_load_lds(
        (const __attribute__((address_space(1))) unsigned int*)g,
        (__attribute__((address_space(3))) unsigned int*)l, 16, 0, 0);
}

// Split gate_w fp32 -> bf16 hi/lo in MFMA-B-fragment-swizzled layout:
// chunk index ((ntile*128 + s)*64 + lane) holds, for lane l:
//   w[e = ntile*16 + (l&15)][k = s*32 + (l>>4)*8 + j], j=0..7  (16 B contiguous)
__global__ __launch_bounds__(256) void prep_w_kernel(
    const float* __restrict__ w, short* __restrict__ w_hi, short* __restrict__ w_lo)
{
    int tid  = blockIdx.x * 256 + threadIdx.x;   // 0..32767
    int lane = tid & 63;
    int s    = (tid >> 6) & (kSteps - 1);
    int nt   = tid >> 13;                        // 0..3
    int e = nt * 16 + (lane & 15);
    int k = s * 32 + (lane >> 4) * 8;
    const float* src = w + (size_t)e * kD + k;
    short8 hi, lo;
#pragma unroll
    for (int j = 0; j < 8; ++j) {
        float xv = src[j];
        uint32_t u  = __builtin_bit_cast(uint32_t, xv);
        uint32_t rh = (u + 0x7FFFu + ((u >> 16) & 1u)) & 0xFFFF0000u;
        hi[j] = (short)(rh >> 16);
        float lf = xv - __builtin_bit_cast(float, rh);   // exact residual
        lo[j] = (short)bf16_rne(lf);
    }
    ((short8*)w_hi)[tid] = hi;
    ((short8*)w_lo)[tid] = lo;
}

// Block: 32 rows x 64 experts, 8 waves. K-loop over 16 buffers of BK=256;
// wave wv computes step (b*8+wv) each buffer for BOTH 16-row M-tiles; x is
// staged in LDS by glds16 (linear dest, pre-swizzled global source).
__global__ __launch_bounds__(512, 2) void router_kernel(
    const float* __restrict__ x, const short8* __restrict__ w_hi,
    const short8* __restrict__ w_lo, const float* __restrict__ temp,
    float* __restrict__ out_mat, float* __restrict__ out_idx)
{
    const int lane = threadIdx.x & 63;
    const int wv   = threadIdx.x >> 6;   // 0..7
    const int quad = lane >> 4;
    const int mr   = lane & 15;
    const int row0 = blockIdx.x * kRows;

    // LDS union: x double-buffer (2*32*256 fl = 64 KiB) / part (8*32*64 fl = 64 KiB)
    __shared__ __align__(16) float smem[2 * kRows * kRowF];
    float (*part)[kRows][kE] = (float (*)[kRows][kE])smem;

    f32x4 acc0[4], acc1[4];
#pragma unroll
    for (int nt = 0; nt < 4; ++nt) {
        acc0[nt] = (f32x4){0.f, 0.f, 0.f, 0.f};
        acc1[nt] = (f32x4){0.f, 0.f, 0.f, 0.f};
    }

    short8 wbh[2][4], wbl[2][4];

    // Prologue: issue buf0 fill (rows 4wv..4wv+3) + w-frags for step wv.
#pragma unroll
    for (int seg = 0; seg < 4; ++seg) {
        const int r = 4 * wv + seg;
        glds16(x + (size_t)(row0 + r) * kD + ((lane * 4) ^ ((r & 7) << 2)),
               &smem[r * kRowF]);
    }
#pragma unroll
    for (int nt = 0; nt < 4; ++nt) {
        wbh[0][nt] = w_hi[(size_t)(nt * kSteps + wv) * 64 + lane];
        wbl[0][nt] = w_lo[(size_t)(nt * kSteps + wv) * 64 + lane];
    }

#pragma unroll 2
    for (int b = 0; b < kBufs; ++b) {
        const int pb = b & 1;
        __syncthreads();   // drains glds for buf b (and w-frag loads for step b)

        if (b + 1 < kBufs) {   // issue buf b+1 fill + w-frags for step b+1
#pragma unroll
            for (int seg = 0; seg < 4; ++seg) {
                const int r = 4 * wv + seg;
                glds16(x + (size_t)(row0 + r) * kD + (b + 1) * kBK
                         + ((lane * 4) ^ ((r & 7) << 2)),
                       &smem[(pb ^ 1) * kRows * kRowF + r * kRowF]);
            }
            const int s = (b + 1) * kWv + wv;
#pragma unroll
            for (int nt = 0; nt < 4; ++nt) {
                wbh[pb ^ 1][nt] = w_hi[(size_t)(nt * kSteps + s) * 64 + lane];
                wbl[pb ^ 1][nt] = w_lo[(size_t)(nt * kSteps + s) * 64 + lane];
            }
        }

        // A frags from LDS (swizzled read): logical cols c0..c0+7 of rows
        // mr (tile 0) and mr+16 (tile 1); (mr+16)&7 == mr&7 -> same XOR.
        const int ss = (mr & 7) << 2;
        const int c0 = wv * 32 + quad * 8;
        const float* bb = &smem[pb * kRows * kRowF];
        f32x4 a0 = *(const f32x4*)&bb[(size_t)mr * kRowF + ((c0) ^ ss)];
        f32x4 a1 = *(const f32x4*)&bb[(size_t)mr * kRowF + ((c0 + 4) ^ ss)];
        f32x4 b0 = *(const f32x4*)&bb[(size_t)(mr + 16) * kRowF + ((c0) ^ ss)];
        f32x4 b1 = *(const f32x4*)&bb[(size_t)(mr + 16) * kRowF + ((c0 + 4) ^ ss)];
        short8 ah0, al0, ah1, al1;
        cvt8(a0, a1, ah0, al0);
        cvt8(b0, b1, ah1, al1);
#pragma unroll
        for (int nt = 0; nt < 4; ++nt) {
            // smallest terms first (same order as passing R1-R4 kernels)
            acc0[nt] = __builtin_amdgcn_mfma_f32_16x16x32_bf16(al0, wbl[pb][nt], acc0[nt], 0, 0, 0);
            acc0[nt] = __builtin_amdgcn_mfma_f32_16x16x32_bf16(al0, wbh[pb][nt], acc0[nt], 0, 0, 0);
            acc0[nt] = __builtin_amdgcn_mfma_f32_16x16x32_bf16(ah0, wbl[pb][nt], acc0[nt], 0, 0, 0);
            acc0[nt] = __builtin_amdgcn_mfma_f32_16x16x32_bf16(ah0, wbh[pb][nt], acc0[nt], 0, 0, 0);
            acc1[nt] = __builtin_amdgcn_mfma_f32_16x16x32_bf16(al1, wbl[pb][nt], acc1[nt], 0, 0, 0);
            acc1[nt] = __builtin_amdgcn_mfma_f32_16x16x32_bf16(al1, wbh[pb][nt], acc1[nt], 0, 0, 0);
            acc1[nt] = __builtin_amdgcn_mfma_f32_16x16x32_bf16(ah1, wbl[pb][nt], acc1[nt], 0, 0, 0);
            acc1[nt] = __builtin_amdgcn_mfma_f32_16x16x32_bf16(ah1, wbh[pb][nt], acc1[nt], 0, 0, 0);
        }
    }

    __syncthreads();   // protect lds_x readers before overlaying part[]

    // Partial-sum reduction across the 8 waves' K-interleaved chunks.
    // C layout (m89-verified): row_in_tile = quad*4 + reg, col = mr.
#pragma unroll
    for (int nt = 0; nt < 4; ++nt)
#pragma unroll
        for (int r = 0; r < 4; ++r) {
            part[wv][quad * 4 + r][nt * 16 + mr]      = acc0[nt][r];
            part[wv][16 + quad * 4 + r][nt * 16 + mr] = acc1[nt][r];
        }
    __syncthreads();

    const float invT = 1.0f / temp[0];
#pragma unroll
    for (int p = 0; p < 4; ++p) {
        const int row = wv + p * kWv;   // wave handles rows wv, wv+8, wv+16, wv+24
        float v = 0.f;
#pragma unroll
        for (int s = 0; s < kWv; ++s)   // ascending wave index: deterministic
            v += part[s][row][lane];

        // Wave-wide top-2 butterfly; tie-break = lowest index (jax top_k).
        float v1 = v; int i1 = lane;
#pragma unroll
        for (int m = 1; m < 64; m <<= 1) {
            float ov = __shfl_xor(v1, m, 64);
            int   oi = __shfl_xor(i1, m, 64);
            if (ov > v1 || (ov == v1 && oi < i1)) { v1 = ov; i1 = oi; }
        }
        float vm = (lane == i1) ? -3.0e38f : v;
        float v2 = vm; int i2 = lane;
#pragma unroll
        for (int m = 1; m < 64; m <<= 1) {
            float ov = __shfl_xor(v2, m, 64);
            int   oi = __shfl_xor(i2, m, 64);
            if (ov > v2 || (ov == v2 && oi < i2)) { v2 = ov; i2 = oi; }
        }

        float e  = expf((v2 - v1) * invT);   // max-subtracted softmax
        float sm = 1.0f + e;
        out_mat[(size_t)(row0 + row) * kE + lane] =
            (lane == i1) ? (1.0f / sm) : ((lane == i2) ? (e / sm) : 0.0f);
        if (lane == 0)
            ((float2*)out_idx)[row0 + row] = make_float2((float)i1, (float)i2);
    }
}

extern "C" void kernel_launch(void* const* d_in, const int* in_sizes, int n_in,
                              void* d_out, int out_size, void* d_ws, size_t ws_size,
                              hipStream_t stream) {
    const float* x    = (const float*)d_in[0];
    const float* gw   = (const float*)d_in[1];
    const float* temp = (const float*)d_in[2];

    float* out_mat = (float*)d_out;                      // [8192,64] fp32
    float* out_idx = (float*)d_out + (size_t)kB * kE;    // [8192,2] idx as float

    short* w_hi = (short*)d_ws;                          // 512 KB
    short* w_lo = w_hi + (size_t)kE * kD;                // 512 KB

    prep_w_kernel<<<128, 256, 0, stream>>>(gw, w_hi, w_lo);

    router_kernel<<<kB / kRows, 512, 0, stream>>>(
        x, (const short8*)w_hi, (const short8*)w_lo, temp, out_mat, out_idx);
}